// Round 4
// baseline (718.956 us; speedup 1.0000x reference)
//
#include <hip/hip_runtime.h>
#include <hip/hip_bf16.h>
#include <stdint.h>

// Problem constants
constexpr int Bb = 2;
constexpr int Ll = 2048;
constexpr int Dd = 1024;
constexpr int Nn = 16;
constexpr int NB = Dd * Nn;    // 16384
constexpr int SL = 64;         // scan segment length
constexpr int NCH = Bb * Dd;   // 2048 channels
constexpr int KCAT = 3 * Dd;   // 3072: [hi|lo|hi] x [Whi|Whi|Wlo]

typedef __bf16 bf16_t;
typedef __bf16 bf16x8 __attribute__((ext_vector_type(8)));
typedef __bf16 bf16x4 __attribute__((ext_vector_type(4)));
typedef float f32x4 __attribute__((ext_vector_type(4)));

// async global->LDS, 16 B per lane. LDS dest = wave-uniform base + lane*16
// (m104/m108); passing per-lane ptr base+lane*16 matches that exactly.
__device__ inline void gld_lds16(const void* g, void* l) {
    __builtin_amdgcn_global_load_lds(
        (const __attribute__((address_space(1))) unsigned int*)g,
        (__attribute__((address_space(3))) unsigned int*)l, 16, 0, 0);
}

// ---------- fp32 -> bf16 conversion (vectorized, grid-stride) ----------
__global__ __launch_bounds__(256) void cvt_bf16(const float* __restrict__ s,
                                                bf16_t* __restrict__ d, int n4) {
    int i = blockIdx.x * 256 + threadIdx.x;
    const int stride = gridDim.x * 256;
    const float4* s4 = (const float4*)s;
    bf16x4* d4 = (bf16x4*)d;
    for (; i < n4; i += stride) {
        float4 v = s4[i];
        bf16x4 o = {(bf16_t)v.x, (bf16_t)v.y, (bf16_t)v.z, (bf16_t)v.w};
        d4[i] = o;
    }
}

// u_cat row = [u_hi (1024) | u_lo (1024) | u_hi (1024)]; also emits u_bf (= hi)
__global__ __launch_bounds__(256) void build_ucat(const float* __restrict__ u,
                                                  bf16_t* __restrict__ ucat,
                                                  bf16_t* __restrict__ ubf) {
    const int i = blockIdx.x * 256 + threadIdx.x;
    const int row = i >> 8;
    const int c = (i & 255) << 2;
    float4 v = ((const float4*)u)[i];
    bf16x4 hi = {(bf16_t)v.x, (bf16_t)v.y, (bf16_t)v.z, (bf16_t)v.w};
    bf16x4 lo = {(bf16_t)(v.x - (float)hi.x), (bf16_t)(v.y - (float)hi.y),
                 (bf16_t)(v.z - (float)hi.z), (bf16_t)(v.w - (float)hi.w)};
    bf16_t* r = ucat + (size_t)row * KCAT;
    *(bf16x4*)(r + c) = hi;
    *(bf16x4*)(r + Dd + c) = lo;
    *(bf16x4*)(r + 2 * Dd + c) = hi;
    *(bf16x4*)(ubf + (size_t)i * 4) = hi;
}

// W_cat row = [W_hi | W_hi | W_lo]
__global__ __launch_bounds__(256) void build_wcat(const float* __restrict__ w,
                                                  bf16_t* __restrict__ wcat) {
    const int i = blockIdx.x * 256 + threadIdx.x;
    const int row = i >> 8;
    const int c = (i & 255) << 2;
    float4 v = ((const float4*)w)[i];
    bf16x4 hi = {(bf16_t)v.x, (bf16_t)v.y, (bf16_t)v.z, (bf16_t)v.w};
    bf16x4 lo = {(bf16_t)(v.x - (float)hi.x), (bf16_t)(v.y - (float)hi.y),
                 (bf16_t)(v.z - (float)hi.z), (bf16_t)(v.w - (float)hi.w)};
    bf16_t* r = wcat + (size_t)row * KCAT;
    *(bf16x4*)(r + c) = hi;
    *(bf16x4*)(r + Dd + c) = hi;
    *(bf16x4*)(r + 2 * Dd + c) = lo;
}

// ---------- legacy 128x128 MFMA GEMM (fallback only, CL%256 != 0) ----------
template <int EP, typename OutT>
__global__ __launch_bounds__(256) void gemm_mfma(
    const bf16_t* __restrict__ Abase, int CL, int l0, int K,
    const bf16_t* __restrict__ W, const float* __restrict__ b1,
    const float* __restrict__ b2, OutT* __restrict__ C, int N)
{
    __shared__ bf16_t As[128 * 32];
    __shared__ bf16_t Bs[128 * 32];

    const int tid = threadIdx.x;
    const int bn = blockIdx.x * 128;
    const int rglob = blockIdx.y * 128;
    const int batch = rglob / CL;
    const int rin = rglob % CL;
    const bf16_t* Ap = Abase + ((size_t)batch * Ll + l0 + rin) * K;
    const bf16_t* Wp = W + (size_t)bn * K;
    OutT* Cp = C + (size_t)rglob * N;

    const int sr = tid >> 2;
    const int sc = (tid & 3) << 3;
    char* ldsA = (char*)As + tid * 16;
    char* ldsB = (char*)Bs + tid * 16;

    const int lane = tid & 63;
    const int wid = tid >> 6;
    const int wm = (wid & 1) << 6;
    const int wn = (wid >> 1) << 6;
    const int lr = lane & 15;
    const int lq = lane >> 4;

    f32x4 acc[4][4] = {};

    for (int k0 = 0; k0 < K; k0 += 32) {
        __syncthreads();
        gld_lds16(Ap + (size_t)sr * K + k0 + sc, ldsA);
        gld_lds16(Ap + (size_t)(sr + 64) * K + k0 + sc, ldsA + 4096);
        gld_lds16(Wp + (size_t)sr * K + k0 + sc, ldsB);
        gld_lds16(Wp + (size_t)(sr + 64) * K + k0 + sc, ldsB + 4096);
        __syncthreads();

        bf16x8 af[4], bfr[4];
#pragma unroll
        for (int mi = 0; mi < 4; ++mi)
            af[mi] = *(const bf16x8*)&As[(wm + mi * 16 + lr) * 32 + lq * 8];
#pragma unroll
        for (int ni = 0; ni < 4; ++ni)
            bfr[ni] = *(const bf16x8*)&Bs[(wn + ni * 16 + lr) * 32 + lq * 8];
#pragma unroll
        for (int mi = 0; mi < 4; ++mi)
#pragma unroll
            for (int ni = 0; ni < 4; ++ni)
                acc[mi][ni] = __builtin_amdgcn_mfma_f32_16x16x32_bf16(
                    af[mi], bfr[ni], acc[mi][ni], 0, 0, 0);
    }

#pragma unroll
    for (int ni = 0; ni < 4; ++ni) {
        const int col = bn + wn + ni * 16 + lr;
        const float bc = b1[col] + (EP == 1 ? b2[col] : 0.f);
#pragma unroll
        for (int mi = 0; mi < 4; ++mi)
#pragma unroll
            for (int i = 0; i < 4; ++i) {
                float v = acc[mi][ni][i] + bc;
                if (EP == 1) v = (v > 20.f) ? v : log1pf(__expf(v));
                Cp[(size_t)(wm + mi * 16 + lq * 4 + i) * N + col] = (OutT)v;
            }
    }
}

// ---------- dt GEMM: 128x64 tile, operand-swapped epilogue ----------
__global__ __launch_bounds__(256) void gemm_dt(
    const bf16_t* __restrict__ A, int K, const bf16_t* __restrict__ W,
    const float* __restrict__ b1, const float* __restrict__ b2,
    float* __restrict__ C)
{
    __shared__ bf16_t As[128 * 32];
    __shared__ bf16_t Bs[64 * 32];

    const int tid = threadIdx.x;
    const int bn = blockIdx.x * 64;
    const int row0 = blockIdx.y * 128;
    const bf16_t* Ap = A + (size_t)row0 * K;
    const bf16_t* Wp = W + (size_t)bn * K;
    float* Cp = C + (size_t)row0 * Dd;

    const int sr = tid >> 2;
    const int sc = (tid & 3) << 3;
    char* ldsA = (char*)As + tid * 16;
    char* ldsB = (char*)Bs + tid * 16;

    const int lane = tid & 63;
    const int wid = tid >> 6;
    const int wm = (wid & 1) << 6;     // 0/64 (rows)
    const int wn = (wid >> 1) << 5;    // 0/32 (cols)
    const int lr = lane & 15;
    const int lq = lane >> 4;

    f32x4 acc[4][2] = {};

    for (int k0 = 0; k0 < K; k0 += 32) {
        __syncthreads();
        gld_lds16(Ap + (size_t)sr * K + k0 + sc, ldsA);
        gld_lds16(Ap + (size_t)(sr + 64) * K + k0 + sc, ldsA + 4096);
        gld_lds16(Wp + (size_t)sr * K + k0 + sc, ldsB);   // 64x32 = 4 KB exactly
        __syncthreads();

        bf16x8 af[4], bfr[2];
#pragma unroll
        for (int mi = 0; mi < 4; ++mi)
            af[mi] = *(const bf16x8*)&As[(wm + mi * 16 + lr) * 32 + lq * 8];
#pragma unroll
        for (int ni = 0; ni < 2; ++ni)
            bfr[ni] = *(const bf16x8*)&Bs[(wn + ni * 16 + lr) * 32 + lq * 8];
#pragma unroll
        for (int mi = 0; mi < 4; ++mi)
#pragma unroll
            for (int ni = 0; ni < 2; ++ni)
                acc[mi][ni] = __builtin_amdgcn_mfma_f32_16x16x32_bf16(
                    bfr[ni], af[mi], acc[mi][ni], 0, 0, 0);   // SWAPPED
    }

    // swapped D layout: row = row0+wm+mi*16+lr, cols = bn+wn+ni*16+lq*4 .. +3
#pragma unroll
    for (int ni = 0; ni < 2; ++ni) {
        const int col = bn + wn + ni * 16 + lq * 4;
        const float4 ba = *(const float4*)&b1[col];
        const float4 bb = *(const float4*)&b2[col];
        const float bc[4] = {ba.x + bb.x, ba.y + bb.y, ba.z + bb.z, ba.w + bb.w};
#pragma unroll
        for (int mi = 0; mi < 4; ++mi) {
            const int row = wm + mi * 16 + lr;
            f32x4 v;
#pragma unroll
            for (int i = 0; i < 4; ++i) {
                float t = acc[mi][ni][i] + bc[i];
                v[i] = (t > 20.f) ? t : log1pf(__expf(t));
            }
            *(f32x4*)(Cp + (size_t)row * Dd + col) = v;
        }
    }
}

// ---------- fused B+C GEMM: 256x128 tile, BK=32, 2 blocks/CU ----------
// Round-3 PMC: 1 block/CU (128KB LDS) left MfmaUtil at 35% with every pipe
// idle -> latency/sync-bound. This variant: LDS 56KB (A dbuf 2x16K, B tbuf
// 3x8K) + acc 64 VGPR/wave -> 2 blocks/CU (16 waves), so one block's
// barrier/vmcnt stalls hide under the other's MFMA. One phase per 32-K-tile:
// {stage A(t+1) x2, stage B(t+2) -> ds_read 8 frags -> barrier -> 16 MFMA
// (setprio) -> vmcnt(1) -> barrier}. vmcnt(1): outstanding = [B(t+1):1,
// A(t+1):2, B(t+2):1]; wait oldest 3, keep B(t+2) in flight (never 0).
// B triple-buffer: B(t+2) lands in slot (bR+2)%3, disjoint from the slot
// being read (bR) and next (bR+1). 64-B LDS rows: swizzle slot = lq ^
// ((lr>>1)&3) with inverse-swizzled global source (both-sides, rule 21);
// uniform 8 lanes per 16B bank-slot -> conflict-free. Operands swapped so
// epilogue packs 4 consecutive cols -> bf16x4 stores.
__global__ __launch_bounds__(512, 4) void gemm256_bc(
    const bf16_t* __restrict__ Abase, int CL, int l0, int K,
    const bf16_t* __restrict__ WB, const bf16_t* __restrict__ WC,
    const float* __restrict__ bB, const float* __restrict__ bC,
    bf16_t* __restrict__ OB, bf16_t* __restrict__ OC)
{
    extern __shared__ char smem[];   // A: [0,32K) as 2x16K; B: [32K,56K) as 3x8K
    const int tid = threadIdx.x;

    // XCD swizzle: 8 consecutive-id blocks land on 8 XCDs; decode so each XCD
    // slot sweeps x-panels with all NY row-panels of a panel co-resident.
    const int NY = (2 * CL) >> 8;              // row-panels (BM=256)
    const int id = blockIdx.x;
    const int cx = id & 7;
    const int jj = id >> 3;
    const int xs_per = (gridDim.x >> 3) / NY;  // x-panels per XCD slot
    const int x = cx * xs_per + jj / NY;       // col-panel 0..255
    const int yb = jj % NY;

    const int rglob = yb * 256;
    const int batch = rglob / CL;
    const int rin = rglob % CL;
    const bf16_t* Ap = Abase + ((size_t)batch * Ll + l0 + rin) * K;

    const bf16_t* Wp; const float* bias; bf16_t* Co; int bn;
    if (x < 128) { Wp = WB; bias = bB; Co = OB; bn = x * 128; }
    else         { Wp = WC; bias = bC; Co = OC; bn = (x - 128) * 128; }
    Wp += (size_t)bn * K;
    bf16_t* Cp = Co + (size_t)rglob * NB;

    const int lane = tid & 63;
    const int wid = tid >> 6;
    const int wr = wid >> 1;       // 0..3  (M quarter, 64 rows)
    const int wc = wid & 1;        // 0..1  (N half, 64 cols)
    const int lr = lane & 15;
    const int lq = lane >> 4;
    const int NT = K >> 5;         // K-tiles of 32

    // staging: one 16B chunk per thread per 128x32 half (8 KB)
    const int r0 = tid >> 2;                                // row 0..127
    const int ksrc = (((tid & 3) ^ ((r0 >> 1) & 3)) << 3);  // inv-swizzled k elems

    auto stageA = [&](int tt, int h) {
        gld_lds16(Ap + (size_t)(h * 128 + r0) * K + tt * 32 + ksrc,
                  smem + (tt & 1) * 16384 + h * 8192 + tid * 16);
    };
    auto stageB = [&](int tt, int slot) {
        gld_lds16(Wp + (size_t)r0 * K + tt * 32 + ksrc,
                  smem + 32768 + slot * 8192 + tid * 16);
    };

    // prologue: A(0)->buf0, B(0)->slot0, B(1)->slot1; wait oldest 3
    stageA(0, 0); stageA(0, 1);
    stageB(0, 0);
    if (NT > 1) {
        stageB(1, 1);
        asm volatile("s_waitcnt vmcnt(1)" ::: "memory");
    } else {
        asm volatile("s_waitcnt vmcnt(0)" ::: "memory");
    }
    __builtin_amdgcn_s_barrier();

    f32x4 acc[4][4] = {};
    const int lqx = (lq << 4) ^ (((lr >> 1) & 3) << 4);  // swizzled byte slot
    int bR = 0;                                          // B read slot

    for (int t = 0; t < NT; ++t) {
        if (t + 1 < NT) { stageA(t + 1, 0); stageA(t + 1, 1); }
        int bS = bR + 2; if (bS >= 3) bS -= 3;
        if (t + 2 < NT) stageB(t + 2, bS);

        const char* Ard = smem + (t & 1) * 16384;
        const char* Brd = smem + 32768 + bR * 8192;
        bf16x8 afr[4], bfr[4];
#pragma unroll
        for (int mi = 0; mi < 4; ++mi) {
            const int row = wr * 64 + mi * 16 + lr;
            afr[mi] = *(const bf16x8*)(Ard + (row >> 7) * 8192 +
                                       (row & 127) * 64 + lqx);
        }
#pragma unroll
        for (int ni = 0; ni < 4; ++ni) {
            const int row = wc * 64 + ni * 16 + lr;
            bfr[ni] = *(const bf16x8*)(Brd + row * 64 + lqx);
        }

        __builtin_amdgcn_s_barrier();
        __builtin_amdgcn_s_setprio(1);
#pragma unroll
        for (int mi = 0; mi < 4; ++mi)
#pragma unroll
            for (int ni = 0; ni < 4; ++ni)
                acc[mi][ni] = __builtin_amdgcn_mfma_f32_16x16x32_bf16(
                    bfr[ni], afr[mi], acc[mi][ni], 0, 0, 0);   // SWAPPED
        __builtin_amdgcn_s_setprio(0);
        if (t + 2 < NT)
            asm volatile("s_waitcnt vmcnt(1)" ::: "memory");
        else if (t + 1 < NT)
            asm volatile("s_waitcnt vmcnt(0)" ::: "memory");
        __builtin_amdgcn_s_barrier();
        bR = bR + 1; if (bR >= 3) bR -= 3;
    }

    // swapped D layout: row = wr*64+mi*16+lr, cols = wc*64+ni*16+lq*4 .. +3
    float4 bv[4];
#pragma unroll
    for (int ni = 0; ni < 4; ++ni)
        bv[ni] = *(const float4*)&bias[bn + wc * 64 + ni * 16 + lq * 4];
#pragma unroll
    for (int mi = 0; mi < 4; ++mi) {
        const size_t rowoff = (size_t)(wr * 64 + mi * 16 + lr) * NB;
#pragma unroll
        for (int ni = 0; ni < 4; ++ni) {
            const int col = bn + wc * 64 + ni * 16 + lq * 4;
            bf16x4 o = {(bf16_t)(acc[mi][ni][0] + bv[ni].x),
                        (bf16_t)(acc[mi][ni][1] + bv[ni].y),
                        (bf16_t)(acc[mi][ni][2] + bv[ni].z),
                        (bf16_t)(acc[mi][ni][3] + bv[ni].w)};
            *(bf16x4*)(Cp + rowoff + col) = o;
        }
    }
}

// ---------- scan pass A: per-segment local scan (h0 = 0) ----------
__global__ __launch_bounds__(256) void scan_seg_local(
    const float* __restrict__ u, const float* __restrict__ dt,
    const bf16_t* __restrict__ Bt_c, const float* __restrict__ log_A,
    float* __restrict__ pseg, float* __restrict__ hseg, int CL, int l0)
{
    const int tid = threadIdx.x;
    const int g = tid >> 4, n = tid & 15;
    const int gid = blockIdx.x * 16 + g;
    const int ch = gid & (NCH - 1);
    const int s = gid >> 11;
    const int b = ch >> 10, d = ch & (Dd - 1);

    const float A = -__expf(log_A[d * Nn + n]);
    const float rA = 1.f / A;

    size_t idx_bn = (size_t)(b * CL + s * SL) * NB + d * Nn + n;
    size_t idx_u = ((size_t)b * Ll + l0 + s * SL) * Dd + d;

    float p = 1.f, h = 0.f;
    for (int l = 0; l < SL; ++l) {
        const float dtv = dt[idx_u];
        const float uv = u[idx_u];
        const float bv = (float)Bt_c[idx_bn];
        const float a = __expf(dtv * A);
        p *= a;
        h = a * h + (a - 1.f) * rA * bv * uv;
        idx_bn += NB; idx_u += Dd;
    }
    const size_t o = ((size_t)s * NCH + ch) * Nn + n;
    pseg[o] = p;
    hseg[o] = h;
}

// ---------- scan pass B: sequential combine across segments ----------
__global__ __launch_bounds__(256) void scan_combine(
    const float* __restrict__ pseg, const float* __restrict__ hseg,
    float* __restrict__ hin_arr, float* __restrict__ h_state,
    int NSEG, int l0)
{
    const int t = blockIdx.x * 256 + threadIdx.x;
    float hin = (l0 == 0) ? 0.f : h_state[t];
    for (int s = 0; s < NSEG; ++s) {
        const size_t o = (size_t)s * (NCH * Nn) + t;
        hin_arr[o] = hin;
        hin = pseg[o] * hin + hseg[o];
    }
    h_state[t] = hin;
}

// ---------- scan pass C: re-run segment from correct h_in, emit y ----------
__global__ __launch_bounds__(256) void scan_seg_final(
    const float* __restrict__ u, const float* __restrict__ dt,
    const bf16_t* __restrict__ Bt_c, const bf16_t* __restrict__ Ct_c,
    const float* __restrict__ log_A, const float* __restrict__ D_skip,
    const float* __restrict__ hin_arr, float* __restrict__ y, int CL, int l0)
{
    const int tid = threadIdx.x;
    const int g = tid >> 4, n = tid & 15;
    const int gid = blockIdx.x * 16 + g;
    const int ch = gid & (NCH - 1);
    const int s = gid >> 11;
    const int b = ch >> 10, d = ch & (Dd - 1);

    const float A = -__expf(log_A[d * Nn + n]);
    const float rA = 1.f / A;
    const float Dsk = D_skip[d];

    size_t idx_bn = (size_t)(b * CL + s * SL) * NB + d * Nn + n;
    size_t idx_u = ((size_t)b * Ll + l0 + s * SL) * Dd + d;

    float h = hin_arr[((size_t)s * NCH + ch) * Nn + n];
    for (int l = 0; l < SL; ++l) {
        const float dtv = dt[idx_u];
        const float uv = u[idx_u];
        const float bv = (float)Bt_c[idx_bn];
        const float cv = (float)Ct_c[idx_bn];
        const float a = __expf(dtv * A);
        h = a * h + (a - 1.f) * rA * bv * uv;
        float p = cv * h;
        p += __shfl_xor(p, 1);
        p += __shfl_xor(p, 2);
        p += __shfl_xor(p, 4);
        p += __shfl_xor(p, 8);
        if (n == 0) y[idx_u] = p + Dsk * uv;
        idx_bn += NB; idx_u += Dd;
    }
}

// ---------- host ----------
static inline size_t al256(size_t x) { return (x + 255) & ~(size_t)255; }

extern "C" void kernel_launch(void* const* d_in, const int* in_sizes, int n_in,
                              void* d_out, int out_size, void* d_ws, size_t ws_size,
                              hipStream_t stream) {
    const float* u       = (const float*)d_in[0];
    const float* log_A   = (const float*)d_in[1];
    const float* D_skip  = (const float*)d_in[2];
    const float* dt_bias = (const float*)d_in[3];
    const float* W_dt    = (const float*)d_in[4];
    const float* b_dt    = (const float*)d_in[5];
    const float* W_B     = (const float*)d_in[6];
    const float* b_B     = (const float*)d_in[7];
    const float* W_C     = (const float*)d_in[8];
    const float* b_C     = (const float*)d_in[9];
    float* y = (float*)d_out;

    // allow 56 KiB dynamic LDS for gemm256_bc (capture-safe host call)
    hipFuncSetAttribute(reinterpret_cast<const void*>(gemm256_bc),
                        hipFuncAttributeMaxDynamicSharedMemorySize, 57344);

    const size_t sz_ubf  = al256((size_t)Bb * Ll * Dd * 2);
    const size_t sz_w    = al256((size_t)NB * Dd * 2);
    const size_t sz_h    = al256((size_t)NCH * Nn * 4);
    const size_t sz_dtf  = al256((size_t)Bb * Ll * Dd * 4);
    const size_t sz_ucat = al256((size_t)Bb * Ll * KCAT * 2);
    const size_t sz_wcat = al256((size_t)Dd * KCAT * 2);

    int CL = 128;
    const int cands[5] = {2048, 1024, 512, 256, 128};
    for (int i = 0; i < 5; ++i) {
        const int c = cands[i];
        const int nseg = c / SL;
        const size_t seg = 3 * al256((size_t)nseg * NCH * Nn * 4);
        const size_t chunk = 2 * al256((size_t)2 * c * NB * 2);
        const size_t ovl = sz_ucat + sz_wcat;
        const size_t need = sz_ubf + 2 * sz_w + sz_h + sz_dtf + seg +
                            (chunk > ovl ? chunk : ovl);
        if (need <= ws_size) { CL = c; break; }
    }
    const int NSEG = CL / SL;

    char* p = (char*)d_ws;
    bf16_t* u_bf   = (bf16_t*)p; p += sz_ubf;
    bf16_t* wB_bf  = (bf16_t*)p; p += sz_w;
    bf16_t* wC_bf  = (bf16_t*)p; p += sz_w;
    float* h_state = (float*)p; p += sz_h;
    float* dt_full = (float*)p; p += sz_dtf;
    const size_t sz_seg1 = al256((size_t)NSEG * NCH * Nn * 4);
    float* pseg    = (float*)p; p += sz_seg1;
    float* hseg    = (float*)p; p += sz_seg1;
    float* hin_arr = (float*)p; p += sz_seg1;
    char* chunk0 = p;
    bf16_t* Bt_c = (bf16_t*)chunk0;
    bf16_t* Ct_c = (bf16_t*)(chunk0 + al256((size_t)2 * CL * NB * 2));
    bf16_t* u_cat = (bf16_t*)chunk0;
    bf16_t* w_cat = (bf16_t*)(chunk0 + sz_ucat);

    cvt_bf16<<<2048, 256, 0, stream>>>(W_B, wB_bf, NB * Dd / 4);
    cvt_bf16<<<2048, 256, 0, stream>>>(W_C, wC_bf, NB * Dd / 4);
    build_ucat<<<Bb * Ll * Dd / 4 / 256, 256, 0, stream>>>(u, u_cat, u_bf);
    build_wcat<<<Dd * Dd / 4 / 256, 256, 0, stream>>>(W_dt, w_cat);

    // dt GEMM: 128x64 tiles -> 512 blocks = 2 blocks/CU
    gemm_dt<<<dim3(Dd / 64, Bb * Ll / 128), 256, 0, stream>>>(
        u_cat, KCAT, w_cat, b_dt, dt_bias, dt_full);

    const bool use256 = (CL % 256 == 0);
    for (int l0 = 0; l0 < Ll; l0 += CL) {
        if (use256) {
            const int NY = 2 * CL / 256;
            gemm256_bc<<<dim3(256 * NY), 512, 57344, stream>>>(
                u_bf, CL, l0, Dd, wB_bf, wC_bf, b_B, b_C, Bt_c, Ct_c);
        } else {
            gemm_mfma<0, bf16_t><<<dim3(NB / 128, 2 * CL / 128), 256, 0, stream>>>(
                u_bf, CL, l0, Dd, wB_bf, b_B, nullptr, Bt_c, NB);
            gemm_mfma<0, bf16_t><<<dim3(NB / 128, 2 * CL / 128), 256, 0, stream>>>(
                u_bf, CL, l0, Dd, wC_bf, b_C, nullptr, Ct_c, NB);
        }
        scan_seg_local<<<dim3(128 * NSEG), 256, 0, stream>>>(
            u, dt_full, Bt_c, log_A, pseg, hseg, CL, l0);
        scan_combine<<<dim3(128), 256, 0, stream>>>(
            pseg, hseg, hin_arr, h_state, NSEG, l0);
        scan_seg_final<<<dim3(128 * NSEG), 256, 0, stream>>>(
            u, dt_full, Bt_c, Ct_c, log_A, D_skip, hin_arr, y, CL, l0);
    }
}

// Round 5
// 672.260 us; speedup vs baseline: 1.0695x; 1.0695x over previous
//
#include <hip/hip_runtime.h>
#include <hip/hip_bf16.h>
#include <stdint.h>

// Problem constants
constexpr int Bb = 2;
constexpr int Ll = 2048;
constexpr int Dd = 1024;
constexpr int Nn = 16;
constexpr int NB = Dd * Nn;    // 16384
constexpr int SL = 64;         // scan segment length
constexpr int NCH = Bb * Dd;   // 2048 channels
constexpr int KCAT = 3 * Dd;   // 3072: [hi|lo|hi] x [Whi|Whi|Wlo]

typedef __bf16 bf16_t;
typedef __bf16 bf16x8 __attribute__((ext_vector_type(8)));
typedef __bf16 bf16x4 __attribute__((ext_vector_type(4)));
typedef float f32x4 __attribute__((ext_vector_type(4)));

// async global->LDS, 16 B per lane. LDS dest = wave-uniform base + lane*16
// (m104/m108); passing per-lane ptr base+lane*16 matches that exactly.
__device__ inline void gld_lds16(const void* g, void* l) {
    __builtin_amdgcn_global_load_lds(
        (const __attribute__((address_space(1))) unsigned int*)g,
        (__attribute__((address_space(3))) unsigned int*)l, 16, 0, 0);
}

// ---------- fp32 -> bf16 conversion (vectorized, grid-stride) ----------
__global__ __launch_bounds__(256) void cvt_bf16(const float* __restrict__ s,
                                                bf16_t* __restrict__ d, int n4) {
    int i = blockIdx.x * 256 + threadIdx.x;
    const int stride = gridDim.x * 256;
    const float4* s4 = (const float4*)s;
    bf16x4* d4 = (bf16x4*)d;
    for (; i < n4; i += stride) {
        float4 v = s4[i];
        bf16x4 o = {(bf16_t)v.x, (bf16_t)v.y, (bf16_t)v.z, (bf16_t)v.w};
        d4[i] = o;
    }
}

// u_cat row = [u_hi (1024) | u_lo (1024) | u_hi (1024)]; also emits u_bf (= hi)
__global__ __launch_bounds__(256) void build_ucat(const float* __restrict__ u,
                                                  bf16_t* __restrict__ ucat,
                                                  bf16_t* __restrict__ ubf) {
    const int i = blockIdx.x * 256 + threadIdx.x;
    const int row = i >> 8;
    const int c = (i & 255) << 2;
    float4 v = ((const float4*)u)[i];
    bf16x4 hi = {(bf16_t)v.x, (bf16_t)v.y, (bf16_t)v.z, (bf16_t)v.w};
    bf16x4 lo = {(bf16_t)(v.x - (float)hi.x), (bf16_t)(v.y - (float)hi.y),
                 (bf16_t)(v.z - (float)hi.z), (bf16_t)(v.w - (float)hi.w)};
    bf16_t* r = ucat + (size_t)row * KCAT;
    *(bf16x4*)(r + c) = hi;
    *(bf16x4*)(r + Dd + c) = lo;
    *(bf16x4*)(r + 2 * Dd + c) = hi;
    *(bf16x4*)(ubf + (size_t)i * 4) = hi;
}

// W_cat row = [W_hi | W_hi | W_lo]
__global__ __launch_bounds__(256) void build_wcat(const float* __restrict__ w,
                                                  bf16_t* __restrict__ wcat) {
    const int i = blockIdx.x * 256 + threadIdx.x;
    const int row = i >> 8;
    const int c = (i & 255) << 2;
    float4 v = ((const float4*)w)[i];
    bf16x4 hi = {(bf16_t)v.x, (bf16_t)v.y, (bf16_t)v.z, (bf16_t)v.w};
    bf16x4 lo = {(bf16_t)(v.x - (float)hi.x), (bf16_t)(v.y - (float)hi.y),
                 (bf16_t)(v.z - (float)hi.z), (bf16_t)(v.w - (float)hi.w)};
    bf16_t* r = wcat + (size_t)row * KCAT;
    *(bf16x4*)(r + c) = hi;
    *(bf16x4*)(r + Dd + c) = hi;
    *(bf16x4*)(r + 2 * Dd + c) = lo;
}

// ---------- legacy 128x128 MFMA GEMM (fallback only, CL%256 != 0) ----------
template <int EP, typename OutT>
__global__ __launch_bounds__(256) void gemm_mfma(
    const bf16_t* __restrict__ Abase, int CL, int l0, int K,
    const bf16_t* __restrict__ W, const float* __restrict__ b1,
    const float* __restrict__ b2, OutT* __restrict__ C, int N)
{
    __shared__ bf16_t As[128 * 32];
    __shared__ bf16_t Bs[128 * 32];

    const int tid = threadIdx.x;
    const int bn = blockIdx.x * 128;
    const int rglob = blockIdx.y * 128;
    const int batch = rglob / CL;
    const int rin = rglob % CL;
    const bf16_t* Ap = Abase + ((size_t)batch * Ll + l0 + rin) * K;
    const bf16_t* Wp = W + (size_t)bn * K;
    OutT* Cp = C + (size_t)rglob * N;

    const int sr = tid >> 2;
    const int sc = (tid & 3) << 3;
    char* ldsA = (char*)As + tid * 16;
    char* ldsB = (char*)Bs + tid * 16;

    const int lane = tid & 63;
    const int wid = tid >> 6;
    const int wm = (wid & 1) << 6;
    const int wn = (wid >> 1) << 6;
    const int lr = lane & 15;
    const int lq = lane >> 4;

    f32x4 acc[4][4] = {};

    for (int k0 = 0; k0 < K; k0 += 32) {
        __syncthreads();
        gld_lds16(Ap + (size_t)sr * K + k0 + sc, ldsA);
        gld_lds16(Ap + (size_t)(sr + 64) * K + k0 + sc, ldsA + 4096);
        gld_lds16(Wp + (size_t)sr * K + k0 + sc, ldsB);
        gld_lds16(Wp + (size_t)(sr + 64) * K + k0 + sc, ldsB + 4096);
        __syncthreads();

        bf16x8 af[4], bfr[4];
#pragma unroll
        for (int mi = 0; mi < 4; ++mi)
            af[mi] = *(const bf16x8*)&As[(wm + mi * 16 + lr) * 32 + lq * 8];
#pragma unroll
        for (int ni = 0; ni < 4; ++ni)
            bfr[ni] = *(const bf16x8*)&Bs[(wn + ni * 16 + lr) * 32 + lq * 8];
#pragma unroll
        for (int mi = 0; mi < 4; ++mi)
#pragma unroll
            for (int ni = 0; ni < 4; ++ni)
                acc[mi][ni] = __builtin_amdgcn_mfma_f32_16x16x32_bf16(
                    af[mi], bfr[ni], acc[mi][ni], 0, 0, 0);
    }

#pragma unroll
    for (int ni = 0; ni < 4; ++ni) {
        const int col = bn + wn + ni * 16 + lr;
        const float bc = b1[col] + (EP == 1 ? b2[col] : 0.f);
#pragma unroll
        for (int mi = 0; mi < 4; ++mi)
#pragma unroll
            for (int i = 0; i < 4; ++i) {
                float v = acc[mi][ni][i] + bc;
                if (EP == 1) v = (v > 20.f) ? v : log1pf(__expf(v));
                Cp[(size_t)(wm + mi * 16 + lq * 4 + i) * N + col] = (OutT)v;
            }
    }
}

// ---------- dt GEMM: 128x128 tile, BK=64, deep pipeline, 2 blocks/CU ----------
// M=4096, N=1024, K=3072 (48 K-tiles, deep). 8 waves (2M x 4N), per-wave
// 64x32 = 4x2 frags, acc 32 VGPR. LDS: A 3-slot (3x16K) + B 2-slot (2x16K)
// = 80 KB -> 2 blocks/CU. Stage A(t+2) at p0, B(t+2) at p2; vmcnt(4) at p3
// leaves A(t+2)+B(t+2) in flight (drains t+1's operands, ~6 phases old).
// Prologue order A0,B0,A1,B1 so vmcnt(4) drains exactly tile-0's operands.
__global__ __launch_bounds__(512, 4) void gemm_dt(
    const bf16_t* __restrict__ A, int K, const bf16_t* __restrict__ W,
    const float* __restrict__ b1, const float* __restrict__ b2,
    float* __restrict__ C)
{
    extern __shared__ char smem[];      // A: [0,48K) 3x16K; B: [48K,80K) 2x16K
    char* const smA = smem;
    char* const smB = smem + 49152;
    const int tid = threadIdx.x;
    const int bn = blockIdx.x * 128;    // col panel
    const int row0 = blockIdx.y * 128;  // row panel
    const bf16_t* Ap = A + (size_t)row0 * K;
    const bf16_t* Wp = W + (size_t)bn * K;
    float* Cp = C + (size_t)row0 * Dd;

    const int lane = tid & 63;
    const int wid = tid >> 6;
    const int wr = wid >> 2;       // 0..1 (64-row half)
    const int wc = wid & 3;        // 0..3 (32-col quarter)
    const int lr = lane & 15;
    const int lq = lane >> 4;
    const int NT = K >> 6;         // 48

    // staging: tile = 128 rows x 64 k = 16 KB = 1024 chunks; 2 per thread
    const int c0 = tid, c1 = tid + 512;
    const int r0 = c0 >> 3, r1 = c1 >> 3;
    const int kb0 = ((c0 & 7) << 3) ^ ((r0 & 7) << 3);
    const int kb1 = ((c1 & 7) << 3) ^ ((r1 & 7) << 3);

    auto stageA = [&](int tt, int slot) {
        gld_lds16(Ap + (size_t)r0 * K + tt * 64 + kb0, smA + slot * 16384 + c0 * 16);
        gld_lds16(Ap + (size_t)r1 * K + tt * 64 + kb1, smA + slot * 16384 + c1 * 16);
    };
    auto stageB = [&](int tt, int slot) {
        gld_lds16(Wp + (size_t)r0 * K + tt * 64 + kb0, smB + slot * 16384 + c0 * 16);
        gld_lds16(Wp + (size_t)r1 * K + tt * 64 + kb1, smB + slot * 16384 + c1 * 16);
    };

    // prologue: A0,B0,A1,B1 -> vmcnt(4) drains A0,B0; leaves A1,B1 in flight
    stageA(0, 0); stageB(0, 0); stageA(1, 1); stageB(1, 1);
    asm volatile("s_waitcnt vmcnt(4)" ::: "memory");
    __builtin_amdgcn_s_barrier();

    f32x4 acc[4][2] = {};
    const int xsw = (lr & 7) << 4;
    int as_rd = 0, as_wr = 2;

    for (int t = 0; t < NT; ++t) {
        const char* Ard = smA + as_rd * 16384;
        const char* Brd = smB + (t & 1) * 16384;

        bf16x8 bfr[2][2];
#pragma unroll
        for (int p = 0; p < 4; ++p) {
            if (p == 0 && t + 2 < NT) stageA(t + 2, as_wr);
            if (p == 2 && t + 2 < NT) stageB(t + 2, (t & 1));  // (t+2)&1 == t&1

            if (p == 0) {
#pragma unroll
                for (int ks = 0; ks < 2; ++ks)
#pragma unroll
                    for (int ni = 0; ni < 2; ++ni)
                        bfr[ks][ni] = *(const bf16x8*)(Brd +
                            (wc * 32 + ni * 16 + lr) * 128 +
                            ((ks * 64 + lq * 16) ^ xsw));
            }
            bf16x8 ak0 = *(const bf16x8*)(Ard +
                (wr * 64 + p * 16 + lr) * 128 + ((lq * 16) ^ xsw));
            bf16x8 ak1 = *(const bf16x8*)(Ard +
                (wr * 64 + p * 16 + lr) * 128 + ((64 + lq * 16) ^ xsw));

            __builtin_amdgcn_s_barrier();
            __builtin_amdgcn_s_setprio(1);
#pragma unroll
            for (int ni = 0; ni < 2; ++ni) {   // SWAPPED operands
                acc[p][ni] = __builtin_amdgcn_mfma_f32_16x16x32_bf16(
                    bfr[0][ni], ak0, acc[p][ni], 0, 0, 0);
                acc[p][ni] = __builtin_amdgcn_mfma_f32_16x16x32_bf16(
                    bfr[1][ni], ak1, acc[p][ni], 0, 0, 0);
            }
            __builtin_amdgcn_s_setprio(0);
            if (p == 3) {
                if (t + 2 < NT)
                    asm volatile("s_waitcnt vmcnt(4)" ::: "memory");
                else if (t + 1 < NT)
                    asm volatile("s_waitcnt vmcnt(0)" ::: "memory");
            }
            __builtin_amdgcn_s_barrier();
        }
        ++as_rd; if (as_rd == 3) as_rd = 0;
        ++as_wr; if (as_wr == 3) as_wr = 0;
    }

    // swapped D: row = row0+wr*64+mi*16+lr, cols = bn+wc*32+ni*16+lq*4 .. +3
#pragma unroll
    for (int ni = 0; ni < 2; ++ni) {
        const int col = bn + wc * 32 + ni * 16 + lq * 4;
        const float4 ba = *(const float4*)&b1[col];
        const float4 bb = *(const float4*)&b2[col];
        const float bc[4] = {ba.x + bb.x, ba.y + bb.y, ba.z + bb.z, ba.w + bb.w};
#pragma unroll
        for (int mi = 0; mi < 4; ++mi) {
            const int row = wr * 64 + mi * 16 + lr;
            f32x4 v;
#pragma unroll
            for (int i = 0; i < 4; ++i) {
                float tv = acc[mi][ni][i] + bc[i];
                v[i] = (tv > 20.f) ? tv : log1pf(__expf(tv));
            }
            *(f32x4*)(Cp + (size_t)row * Dd + col) = v;
        }
    }
}

// ---------- fused B+C GEMM: 256x256, BK=64, A 3-slot deep pipeline ----------
// Round-3 structure (verified, 166us) + the A-depth fix: round-3 staged
// A(t+1) at p0/p1 and drained it at p3 vmcnt(4) -> only ~700 cyc cover while
// A hits L3 (L2 thrashed by W stream) -> every-tile stall (MfmaUtil 35%, all
// pipes idle; round-4 showed occupancy doesn't fix it). Now: A triple-buffer
// (3x32K) + B double-buffer (2x32K) = 160 KB LDS (full CU; 160KB/WG is valid,
// cf. AITER attn m243). Stage A(t+2) at p0/p1 -> ~2000 cyc cover; B(t+2) at
// p2/p3 (unchanged). vmcnt(8) at p3 leaves {A(t+2),B(t+2)} in flight and
// drains t+1's operands, which are 6-8 phases old -> wait nearly free.
// Prologue order A0,B0,A1,B1 so vmcnt(8) drains exactly tile-0's operands.
__global__ __launch_bounds__(512, 2) void gemm256_bc(
    const bf16_t* __restrict__ Abase, int CL, int l0, int K,
    const bf16_t* __restrict__ WB, const bf16_t* __restrict__ WC,
    const float* __restrict__ bB, const float* __restrict__ bC,
    bf16_t* __restrict__ OB, bf16_t* __restrict__ OC)
{
    extern __shared__ char smem[];   // A: [0,96K) 3x32K; B: [96K,160K) 2x32K
    char* const smA = smem;
    char* const smB = smem + 98304;
    const int tid = threadIdx.x;

    // block decode with XCD swizzle (bijective: 128*NY blocks, NY*16 per XCD)
    const int NY = (2 * CL) >> 8;
    const int id = blockIdx.x;
    const int cx = id & 7;
    const int jj = id >> 3;
    const int x = cx * 16 + jj / NY;    // col-panel 0..127
    const int yb = jj % NY;             // row-panel

    const int rglob = yb * 256;
    const int batch = rglob / CL;
    const int rin = rglob % CL;
    const bf16_t* Ap = Abase + ((size_t)batch * Ll + l0 + rin) * K;

    const bf16_t* Wp; const float* bias; bf16_t* Co; int bn;
    if (x < 64) { Wp = WB; bias = bB; Co = OB; bn = x * 256; }
    else        { Wp = WC; bias = bC; Co = OC; bn = (x - 64) * 256; }
    Wp += (size_t)bn * K;
    bf16_t* Cp = Co + (size_t)rglob * NB;

    const int lane = tid & 63;
    const int wid = tid >> 6;
    const int wr = wid >> 2;       // 0..1  (M half)
    const int wc = wid & 3;        // 0..3  (N quarter)
    const int lr = lane & 15;
    const int lq = lane >> 4;
    const int NT = K >> 6;         // K-tiles of 64 (16)

    // staging: 2 chunks of 16B per thread per half-tile (128 rows x 64 k)
    const int c0 = tid, c1 = tid + 512;
    const int r0 = c0 >> 3, r1 = c1 >> 3;
    const int kb0 = ((c0 & 7) << 3) ^ ((r0 & 7) << 3);   // inverse-swizzled src
    const int kb1 = ((c1 & 7) << 3) ^ ((r1 & 7) << 3);

    auto stageA = [&](int tt, int slot, int h) {
        gld_lds16(Ap + (size_t)(h * 128 + r0) * K + tt * 64 + kb0,
                  smA + slot * 32768 + h * 16384 + c0 * 16);
        gld_lds16(Ap + (size_t)(h * 128 + r1) * K + tt * 64 + kb1,
                  smA + slot * 32768 + h * 16384 + c1 * 16);
    };
    auto stageB = [&](int tt, int slot, int h) {
        gld_lds16(Wp + (size_t)(h * 128 + r0) * K + tt * 64 + kb0,
                  smB + slot * 32768 + h * 16384 + c0 * 16);
        gld_lds16(Wp + (size_t)(h * 128 + r1) * K + tt * 64 + kb1,
                  smB + slot * 32768 + h * 16384 + c1 * 16);
    };

    // prologue: A0,B0,A1,B1 (4 loads each) -> vmcnt(8) drains A0,B0
    stageA(0, 0, 0); stageA(0, 0, 1);
    stageB(0, 0, 0); stageB(0, 0, 1);
    stageA(1, 1, 0); stageA(1, 1, 1);
    stageB(1, 1, 0); stageB(1, 1, 1);
    asm volatile("s_waitcnt vmcnt(8)" ::: "memory");
    __builtin_amdgcn_s_barrier();

    f32x4 acc[8][4] = {};
    const int xsw = (lr & 7) << 4;     // read-side XOR swizzle (bytes)
    int as_rd = 0, as_wr = 2;

    for (int t = 0; t < NT; ++t) {
        const char* Ard = smA + as_rd * 32768;
        const char* Brd = smB + (t & 1) * 32768;

        bf16x8 bfr[2][4];
#pragma unroll
        for (int p = 0; p < 4; ++p) {
            // stage one half-tile, 2 tiles ahead (A at p0/p1, B at p2/p3)
            if (p == 0) { if (t + 2 < NT) stageA(t + 2, as_wr, 0); }
            if (p == 1) { if (t + 2 < NT) stageA(t + 2, as_wr, 1); }
            if (p == 2) { if (t + 2 < NT) stageB(t + 2, (t & 1), 0); }
            if (p == 3) { if (t + 2 < NT) stageB(t + 2, (t & 1), 1); }

            if (p == 0) {
#pragma unroll
                for (int ks = 0; ks < 2; ++ks)
#pragma unroll
                    for (int ni = 0; ni < 4; ++ni)
                        bfr[ks][ni] = *(const bf16x8*)(Brd +
                            (wc * 64 + ni * 16 + lr) * 128 +
                            ((ks * 64 + lq * 16) ^ xsw));
            }
            bf16x8 a0k0 = *(const bf16x8*)(Ard +
                (wr * 128 + (2 * p) * 16 + lr) * 128 + ((lq * 16) ^ xsw));
            bf16x8 a0k1 = *(const bf16x8*)(Ard +
                (wr * 128 + (2 * p) * 16 + lr) * 128 + ((64 + lq * 16) ^ xsw));
            bf16x8 a1k0 = *(const bf16x8*)(Ard +
                (wr * 128 + (2 * p + 1) * 16 + lr) * 128 + ((lq * 16) ^ xsw));
            bf16x8 a1k1 = *(const bf16x8*)(Ard +
                (wr * 128 + (2 * p + 1) * 16 + lr) * 128 + ((64 + lq * 16) ^ xsw));

            __builtin_amdgcn_s_barrier();
            __builtin_amdgcn_s_setprio(1);
#pragma unroll
            for (int ni = 0; ni < 4; ++ni) {   // SWAPPED operands
                acc[2 * p][ni] = __builtin_amdgcn_mfma_f32_16x16x32_bf16(
                    bfr[0][ni], a0k0, acc[2 * p][ni], 0, 0, 0);
                acc[2 * p][ni] = __builtin_amdgcn_mfma_f32_16x16x32_bf16(
                    bfr[1][ni], a0k1, acc[2 * p][ni], 0, 0, 0);
                acc[2 * p + 1][ni] = __builtin_amdgcn_mfma_f32_16x16x32_bf16(
                    bfr[0][ni], a1k0, acc[2 * p + 1][ni], 0, 0, 0);
                acc[2 * p + 1][ni] = __builtin_amdgcn_mfma_f32_16x16x32_bf16(
                    bfr[1][ni], a1k1, acc[2 * p + 1][ni], 0, 0, 0);
            }
            __builtin_amdgcn_s_setprio(0);
            if (p == 3) {
                if (t + 2 < NT)
                    asm volatile("s_waitcnt vmcnt(8)" ::: "memory");
                else if (t + 1 < NT)
                    asm volatile("s_waitcnt vmcnt(0)" ::: "memory");
            }
            __builtin_amdgcn_s_barrier();
        }
        ++as_rd; if (as_rd == 3) as_rd = 0;
        ++as_wr; if (as_wr == 3) as_wr = 0;
    }

    // swapped D layout: row = wr*128+mi*16+lr, cols = wc*64+ni*16+lq*4 .. +3
    float4 bv[4];
#pragma unroll
    for (int ni = 0; ni < 4; ++ni)
        bv[ni] = *(const float4*)&bias[bn + wc * 64 + ni * 16 + lq * 4];
#pragma unroll
    for (int mi = 0; mi < 8; ++mi) {
        const size_t rowoff = (size_t)(wr * 128 + mi * 16 + lr) * NB;
#pragma unroll
        for (int ni = 0; ni < 4; ++ni) {
            const int col = bn + wc * 64 + ni * 16 + lq * 4;
            bf16x4 o = {(bf16_t)(acc[mi][ni][0] + bv[ni].x),
                        (bf16_t)(acc[mi][ni][1] + bv[ni].y),
                        (bf16_t)(acc[mi][ni][2] + bv[ni].z),
                        (bf16_t)(acc[mi][ni][3] + bv[ni].w)};
            *(bf16x4*)(Cp + rowoff + col) = o;
        }
    }
}

// ---------- scan pass A: per-segment local scan (h0 = 0) ----------
__global__ __launch_bounds__(256) void scan_seg_local(
    const float* __restrict__ u, const float* __restrict__ dt,
    const bf16_t* __restrict__ Bt_c, const float* __restrict__ log_A,
    float* __restrict__ pseg, float* __restrict__ hseg, int CL, int l0)
{
    const int tid = threadIdx.x;
    const int g = tid >> 4, n = tid & 15;
    const int gid = blockIdx.x * 16 + g;
    const int ch = gid & (NCH - 1);
    const int s = gid >> 11;
    const int b = ch >> 10, d = ch & (Dd - 1);

    const float A = -__expf(log_A[d * Nn + n]);
    const float rA = 1.f / A;

    size_t idx_bn = (size_t)(b * CL + s * SL) * NB + d * Nn + n;
    size_t idx_u = ((size_t)b * Ll + l0 + s * SL) * Dd + d;

    float p = 1.f, h = 0.f;
    for (int l = 0; l < SL; ++l) {
        const float dtv = dt[idx_u];
        const float uv = u[idx_u];
        const float bv = (float)Bt_c[idx_bn];
        const float a = __expf(dtv * A);
        p *= a;
        h = a * h + (a - 1.f) * rA * bv * uv;
        idx_bn += NB; idx_u += Dd;
    }
    const size_t o = ((size_t)s * NCH + ch) * Nn + n;
    pseg[o] = p;
    hseg[o] = h;
}

// ---------- scan pass B: sequential combine across segments ----------
__global__ __launch_bounds__(256) void scan_combine(
    const float* __restrict__ pseg, const float* __restrict__ hseg,
    float* __restrict__ hin_arr, float* __restrict__ h_state,
    int NSEG, int l0)
{
    const int t = blockIdx.x * 256 + threadIdx.x;
    float hin = (l0 == 0) ? 0.f : h_state[t];
    for (int s = 0; s < NSEG; ++s) {
        const size_t o = (size_t)s * (NCH * Nn) + t;
        hin_arr[o] = hin;
        hin = pseg[o] * hin + hseg[o];
    }
    h_state[t] = hin;
}

// ---------- scan pass C: re-run segment from correct h_in, emit y ----------
__global__ __launch_bounds__(256) void scan_seg_final(
    const float* __restrict__ u, const float* __restrict__ dt,
    const bf16_t* __restrict__ Bt_c, const bf16_t* __restrict__ Ct_c,
    const float* __restrict__ log_A, const float* __restrict__ D_skip,
    const float* __restrict__ hin_arr, float* __restrict__ y, int CL, int l0)
{
    const int tid = threadIdx.x;
    const int g = tid >> 4, n = tid & 15;
    const int gid = blockIdx.x * 16 + g;
    const int ch = gid & (NCH - 1);
    const int s = gid >> 11;
    const int b = ch >> 10, d = ch & (Dd - 1);

    const float A = -__expf(log_A[d * Nn + n]);
    const float rA = 1.f / A;
    const float Dsk = D_skip[d];

    size_t idx_bn = (size_t)(b * CL + s * SL) * NB + d * Nn + n;
    size_t idx_u = ((size_t)b * Ll + l0 + s * SL) * Dd + d;

    float h = hin_arr[((size_t)s * NCH + ch) * Nn + n];
    for (int l = 0; l < SL; ++l) {
        const float dtv = dt[idx_u];
        const float uv = u[idx_u];
        const float bv = (float)Bt_c[idx_bn];
        const float cv = (float)Ct_c[idx_bn];
        const float a = __expf(dtv * A);
        h = a * h + (a - 1.f) * rA * bv * uv;
        float p = cv * h;
        p += __shfl_xor(p, 1);
        p += __shfl_xor(p, 2);
        p += __shfl_xor(p, 4);
        p += __shfl_xor(p, 8);
        if (n == 0) y[idx_u] = p + Dsk * uv;
        idx_bn += NB; idx_u += Dd;
    }
}

// ---------- host ----------
static inline size_t al256(size_t x) { return (x + 255) & ~(size_t)255; }

extern "C" void kernel_launch(void* const* d_in, const int* in_sizes, int n_in,
                              void* d_out, int out_size, void* d_ws, size_t ws_size,
                              hipStream_t stream) {
    const float* u       = (const float*)d_in[0];
    const float* log_A   = (const float*)d_in[1];
    const float* D_skip  = (const float*)d_in[2];
    const float* dt_bias = (const float*)d_in[3];
    const float* W_dt    = (const float*)d_in[4];
    const float* b_dt    = (const float*)d_in[5];
    const float* W_B     = (const float*)d_in[6];
    const float* b_B     = (const float*)d_in[7];
    const float* W_C     = (const float*)d_in[8];
    const float* b_C     = (const float*)d_in[9];
    float* y = (float*)d_out;

    // dynamic LDS opt-in (capture-safe host calls)
    hipFuncSetAttribute(reinterpret_cast<const void*>(gemm256_bc),
                        hipFuncAttributeMaxDynamicSharedMemorySize, 163840);
    hipFuncSetAttribute(reinterpret_cast<const void*>(gemm_dt),
                        hipFuncAttributeMaxDynamicSharedMemorySize, 81920);

    const size_t sz_ubf  = al256((size_t)Bb * Ll * Dd * 2);
    const size_t sz_w    = al256((size_t)NB * Dd * 2);
    const size_t sz_h    = al256((size_t)NCH * Nn * 4);
    const size_t sz_dtf  = al256((size_t)Bb * Ll * Dd * 4);
    const size_t sz_ucat = al256((size_t)Bb * Ll * KCAT * 2);
    const size_t sz_wcat = al256((size_t)Dd * KCAT * 2);

    int CL = 128;
    const int cands[5] = {2048, 1024, 512, 256, 128};
    for (int i = 0; i < 5; ++i) {
        const int c = cands[i];
        const int nseg = c / SL;
        const size_t seg = 3 * al256((size_t)nseg * NCH * Nn * 4);
        const size_t chunk = 2 * al256((size_t)2 * c * NB * 2);
        const size_t ovl = sz_ucat + sz_wcat;
        const size_t need = sz_ubf + 2 * sz_w + sz_h + sz_dtf + seg +
                            (chunk > ovl ? chunk : ovl);
        if (need <= ws_size) { CL = c; break; }
    }
    const int NSEG = CL / SL;

    char* p = (char*)d_ws;
    bf16_t* u_bf   = (bf16_t*)p; p += sz_ubf;
    bf16_t* wB_bf  = (bf16_t*)p; p += sz_w;
    bf16_t* wC_bf  = (bf16_t*)p; p += sz_w;
    float* h_state = (float*)p; p += sz_h;
    float* dt_full = (float*)p; p += sz_dtf;
    const size_t sz_seg1 = al256((size_t)NSEG * NCH * Nn * 4);
    float* pseg    = (float*)p; p += sz_seg1;
    float* hseg    = (float*)p; p += sz_seg1;
    float* hin_arr = (float*)p; p += sz_seg1;
    char* chunk0 = p;
    bf16_t* Bt_c = (bf16_t*)chunk0;
    bf16_t* Ct_c = (bf16_t*)(chunk0 + al256((size_t)2 * CL * NB * 2));
    bf16_t* u_cat = (bf16_t*)chunk0;
    bf16_t* w_cat = (bf16_t*)(chunk0 + sz_ucat);

    cvt_bf16<<<2048, 256, 0, stream>>>(W_B, wB_bf, NB * Dd / 4);
    cvt_bf16<<<2048, 256, 0, stream>>>(W_C, wC_bf, NB * Dd / 4);
    build_ucat<<<Bb * Ll * Dd / 4 / 256, 256, 0, stream>>>(u, u_cat, u_bf);
    build_wcat<<<Dd * Dd / 4 / 256, 256, 0, stream>>>(W_dt, w_cat);

    // dt GEMM: 128x128 tiles, deep-pipelined, 2 blocks/CU
    gemm_dt<<<dim3(Dd / 128, Bb * Ll / 128), 512, 81920, stream>>>(
        u_cat, KCAT, w_cat, b_dt, dt_bias, dt_full);

    const bool use256 = (CL % 256 == 0);
    for (int l0 = 0; l0 < Ll; l0 += CL) {
        if (use256) {
            const int NY = 2 * CL / 256;
            gemm256_bc<<<dim3(128 * NY), 512, 163840, stream>>>(
                u_bf, CL, l0, Dd, wB_bf, wC_bf, b_B, b_C, Bt_c, Ct_c);
        } else {
            gemm_mfma<0, bf16_t><<<dim3(NB / 128, 2 * CL / 128), 256, 0, stream>>>(
                u_bf, CL, l0, Dd, wB_bf, b_B, nullptr, Bt_c, NB);
            gemm_mfma<0, bf16_t><<<dim3(NB / 128, 2 * CL / 128), 256, 0, stream>>>(
                u_bf, CL, l0, Dd, wC_bf, b_C, nullptr, Ct_c, NB);
        }
        scan_seg_local<<<dim3(128 * NSEG), 256, 0, stream>>>(
            u, dt_full, Bt_c, log_A, pseg, hseg, CL, l0);
        scan_combine<<<dim3(128), 256, 0, stream>>>(
            pseg, hseg, hin_arr, h_state, NSEG, l0);
        scan_seg_final<<<dim3(128 * NSEG), 256, 0, stream>>>(
            u, dt_full, Bt_c, Ct_c, log_A, D_skip, hin_arr, y, CL, l0);
    }
}

// Round 6
// 670.597 us; speedup vs baseline: 1.0721x; 1.0025x over previous
//
#include <hip/hip_runtime.h>
#include <hip/hip_bf16.h>
#include <stdint.h>

// Problem constants
constexpr int Bb = 2;
constexpr int Ll = 2048;
constexpr int Dd = 1024;
constexpr int Nn = 16;
constexpr int NB = Dd * Nn;    // 16384
constexpr int SL = 64;         // scan segment length
constexpr int NCH = Bb * Dd;   // 2048 channels
constexpr int KCAT = 3 * Dd;   // 3072: [hi|lo|hi] x [Whi|Whi|Wlo]

typedef __bf16 bf16_t;
typedef __bf16 bf16x8 __attribute__((ext_vector_type(8)));
typedef __bf16 bf16x4 __attribute__((ext_vector_type(4)));
typedef float f32x4 __attribute__((ext_vector_type(4)));

// async global->LDS, 16 B per lane. LDS dest = wave-uniform base + lane*16
// (m104/m108); passing per-lane ptr base+lane*16 matches that exactly.
__device__ inline void gld_lds16(const void* g, void* l) {
    __builtin_amdgcn_global_load_lds(
        (const __attribute__((address_space(1))) unsigned int*)g,
        (__attribute__((address_space(3))) unsigned int*)l, 16, 0, 0);
}

// ---------- fp32 -> bf16 conversion (vectorized, grid-stride) ----------
__global__ __launch_bounds__(256) void cvt_bf16(const float* __restrict__ s,
                                                bf16_t* __restrict__ d, int n4) {
    int i = blockIdx.x * 256 + threadIdx.x;
    const int stride = gridDim.x * 256;
    const float4* s4 = (const float4*)s;
    bf16x4* d4 = (bf16x4*)d;
    for (; i < n4; i += stride) {
        float4 v = s4[i];
        bf16x4 o = {(bf16_t)v.x, (bf16_t)v.y, (bf16_t)v.z, (bf16_t)v.w};
        d4[i] = o;
    }
}

// u_cat row = [u_hi (1024) | u_lo (1024) | u_hi (1024)]; also emits u_bf (= hi)
__global__ __launch_bounds__(256) void build_ucat(const float* __restrict__ u,
                                                  bf16_t* __restrict__ ucat,
                                                  bf16_t* __restrict__ ubf) {
    const int i = blockIdx.x * 256 + threadIdx.x;
    const int row = i >> 8;
    const int c = (i & 255) << 2;
    float4 v = ((const float4*)u)[i];
    bf16x4 hi = {(bf16_t)v.x, (bf16_t)v.y, (bf16_t)v.z, (bf16_t)v.w};
    bf16x4 lo = {(bf16_t)(v.x - (float)hi.x), (bf16_t)(v.y - (float)hi.y),
                 (bf16_t)(v.z - (float)hi.z), (bf16_t)(v.w - (float)hi.w)};
    bf16_t* r = ucat + (size_t)row * KCAT;
    *(bf16x4*)(r + c) = hi;
    *(bf16x4*)(r + Dd + c) = lo;
    *(bf16x4*)(r + 2 * Dd + c) = hi;
    *(bf16x4*)(ubf + (size_t)i * 4) = hi;
}

// W_cat row = [W_hi | W_hi | W_lo]
__global__ __launch_bounds__(256) void build_wcat(const float* __restrict__ w,
                                                  bf16_t* __restrict__ wcat) {
    const int i = blockIdx.x * 256 + threadIdx.x;
    const int row = i >> 8;
    const int c = (i & 255) << 2;
    float4 v = ((const float4*)w)[i];
    bf16x4 hi = {(bf16_t)v.x, (bf16_t)v.y, (bf16_t)v.z, (bf16_t)v.w};
    bf16x4 lo = {(bf16_t)(v.x - (float)hi.x), (bf16_t)(v.y - (float)hi.y),
                 (bf16_t)(v.z - (float)hi.z), (bf16_t)(v.w - (float)hi.w)};
    bf16_t* r = wcat + (size_t)row * KCAT;
    *(bf16x4*)(r + c) = hi;
    *(bf16x4*)(r + Dd + c) = hi;
    *(bf16x4*)(r + 2 * Dd + c) = lo;
}

// ---------- legacy 128x128 MFMA GEMM (fallback only, CL%256 != 0) ----------
template <int EP, typename OutT>
__global__ __launch_bounds__(256) void gemm_mfma(
    const bf16_t* __restrict__ Abase, int CL, int l0, int K,
    const bf16_t* __restrict__ W, const float* __restrict__ b1,
    const float* __restrict__ b2, OutT* __restrict__ C, int N)
{
    __shared__ bf16_t As[128 * 32];
    __shared__ bf16_t Bs[128 * 32];

    const int tid = threadIdx.x;
    const int bn = blockIdx.x * 128;
    const int rglob = blockIdx.y * 128;
    const int batch = rglob / CL;
    const int rin = rglob % CL;
    const bf16_t* Ap = Abase + ((size_t)batch * Ll + l0 + rin) * K;
    const bf16_t* Wp = W + (size_t)bn * K;
    OutT* Cp = C + (size_t)rglob * N;

    const int sr = tid >> 2;
    const int sc = (tid & 3) << 3;
    char* ldsA = (char*)As + tid * 16;
    char* ldsB = (char*)Bs + tid * 16;

    const int lane = tid & 63;
    const int wid = tid >> 6;
    const int wm = (wid & 1) << 6;
    const int wn = (wid >> 1) << 6;
    const int lr = lane & 15;
    const int lq = lane >> 4;

    f32x4 acc[4][4] = {};

    for (int k0 = 0; k0 < K; k0 += 32) {
        __syncthreads();
        gld_lds16(Ap + (size_t)sr * K + k0 + sc, ldsA);
        gld_lds16(Ap + (size_t)(sr + 64) * K + k0 + sc, ldsA + 4096);
        gld_lds16(Wp + (size_t)sr * K + k0 + sc, ldsB);
        gld_lds16(Wp + (size_t)(sr + 64) * K + k0 + sc, ldsB + 4096);
        __syncthreads();

        bf16x8 af[4], bfr[4];
#pragma unroll
        for (int mi = 0; mi < 4; ++mi)
            af[mi] = *(const bf16x8*)&As[(wm + mi * 16 + lr) * 32 + lq * 8];
#pragma unroll
        for (int ni = 0; ni < 4; ++ni)
            bfr[ni] = *(const bf16x8*)&Bs[(wn + ni * 16 + lr) * 32 + lq * 8];
#pragma unroll
        for (int mi = 0; mi < 4; ++mi)
#pragma unroll
            for (int ni = 0; ni < 4; ++ni)
                acc[mi][ni] = __builtin_amdgcn_mfma_f32_16x16x32_bf16(
                    af[mi], bfr[ni], acc[mi][ni], 0, 0, 0);
    }

#pragma unroll
    for (int ni = 0; ni < 4; ++ni) {
        const int col = bn + wn + ni * 16 + lr;
        const float bc = b1[col] + (EP == 1 ? b2[col] : 0.f);
#pragma unroll
        for (int mi = 0; mi < 4; ++mi)
#pragma unroll
            for (int i = 0; i < 4; ++i) {
                float v = acc[mi][ni][i] + bc;
                if (EP == 1) v = (v > 20.f) ? v : log1pf(__expf(v));
                Cp[(size_t)(wm + mi * 16 + lq * 4 + i) * N + col] = (OutT)v;
            }
    }
}

// ---------- dt GEMM: 128x128 tile, BK=64, deep pipeline, 2 blocks/CU ----------
// (verified round 5: dt left the top-5)
__global__ __launch_bounds__(512, 4) void gemm_dt(
    const bf16_t* __restrict__ A, int K, const bf16_t* __restrict__ W,
    const float* __restrict__ b1, const float* __restrict__ b2,
    float* __restrict__ C)
{
    extern __shared__ char smem[];      // A: [0,48K) 3x16K; B: [48K,80K) 2x16K
    char* const smA = smem;
    char* const smB = smem + 49152;
    const int tid = threadIdx.x;
    const int bn = blockIdx.x * 128;    // col panel
    const int row0 = blockIdx.y * 128;  // row panel
    const bf16_t* Ap = A + (size_t)row0 * K;
    const bf16_t* Wp = W + (size_t)bn * K;
    float* Cp = C + (size_t)row0 * Dd;

    const int lane = tid & 63;
    const int wid = tid >> 6;
    const int wr = wid >> 2;       // 0..1 (64-row half)
    const int wc = wid & 3;        // 0..3 (32-col quarter)
    const int lr = lane & 15;
    const int lq = lane >> 4;
    const int NT = K >> 6;         // 48

    const int c0 = tid, c1 = tid + 512;
    const int r0 = c0 >> 3, r1 = c1 >> 3;
    const int kb0 = ((c0 & 7) << 3) ^ ((r0 & 7) << 3);
    const int kb1 = ((c1 & 7) << 3) ^ ((r1 & 7) << 3);

    auto stageA = [&](int tt, int slot) {
        gld_lds16(Ap + (size_t)r0 * K + tt * 64 + kb0, smA + slot * 16384 + c0 * 16);
        gld_lds16(Ap + (size_t)r1 * K + tt * 64 + kb1, smA + slot * 16384 + c1 * 16);
    };
    auto stageB = [&](int tt, int slot) {
        gld_lds16(Wp + (size_t)r0 * K + tt * 64 + kb0, smB + slot * 16384 + c0 * 16);
        gld_lds16(Wp + (size_t)r1 * K + tt * 64 + kb1, smB + slot * 16384 + c1 * 16);
    };

    stageA(0, 0); stageB(0, 0); stageA(1, 1); stageB(1, 1);
    asm volatile("s_waitcnt vmcnt(4)" ::: "memory");
    __builtin_amdgcn_s_barrier();

    f32x4 acc[4][2] = {};
    const int xsw = (lr & 7) << 4;
    int as_rd = 0, as_wr = 2;

    for (int t = 0; t < NT; ++t) {
        const char* Ard = smA + as_rd * 16384;
        const char* Brd = smB + (t & 1) * 16384;

        bf16x8 bfr[2][2];
#pragma unroll
        for (int p = 0; p < 4; ++p) {
            if (p == 0 && t + 2 < NT) stageA(t + 2, as_wr);
            if (p == 2 && t + 2 < NT) stageB(t + 2, (t & 1));  // (t+2)&1 == t&1

            if (p == 0) {
#pragma unroll
                for (int ks = 0; ks < 2; ++ks)
#pragma unroll
                    for (int ni = 0; ni < 2; ++ni)
                        bfr[ks][ni] = *(const bf16x8*)(Brd +
                            (wc * 32 + ni * 16 + lr) * 128 +
                            ((ks * 64 + lq * 16) ^ xsw));
            }
            bf16x8 ak0 = *(const bf16x8*)(Brd == nullptr ? nullptr : (Ard +
                (wr * 64 + p * 16 + lr) * 128 + ((lq * 16) ^ xsw)));
            bf16x8 ak1 = *(const bf16x8*)(Ard +
                (wr * 64 + p * 16 + lr) * 128 + ((64 + lq * 16) ^ xsw));

            __builtin_amdgcn_s_barrier();
            __builtin_amdgcn_s_setprio(1);
#pragma unroll
            for (int ni = 0; ni < 2; ++ni) {   // SWAPPED operands
                acc[p][ni] = __builtin_amdgcn_mfma_f32_16x16x32_bf16(
                    bfr[0][ni], ak0, acc[p][ni], 0, 0, 0);
                acc[p][ni] = __builtin_amdgcn_mfma_f32_16x16x32_bf16(
                    bfr[1][ni], ak1, acc[p][ni], 0, 0, 0);
            }
            __builtin_amdgcn_s_setprio(0);
            if (p == 3) {
                if (t + 2 < NT)
                    asm volatile("s_waitcnt vmcnt(4)" ::: "memory");
                else if (t + 1 < NT)
                    asm volatile("s_waitcnt vmcnt(0)" ::: "memory");
            }
            __builtin_amdgcn_s_barrier();
        }
        ++as_rd; if (as_rd == 3) as_rd = 0;
        ++as_wr; if (as_wr == 3) as_wr = 0;
    }

#pragma unroll
    for (int ni = 0; ni < 2; ++ni) {
        const int col = bn + wc * 32 + ni * 16 + lq * 4;
        const float4 ba = *(const float4*)&b1[col];
        const float4 bb = *(const float4*)&b2[col];
        const float bc[4] = {ba.x + bb.x, ba.y + bb.y, ba.z + bb.z, ba.w + bb.w};
#pragma unroll
        for (int mi = 0; mi < 4; ++mi) {
            const int row = wr * 64 + mi * 16 + lr;
            f32x4 v;
#pragma unroll
            for (int i = 0; i < 4; ++i) {
                float tv = acc[mi][ni][i] + bc[i];
                v[i] = (tv > 20.f) ? tv : log1pf(__expf(tv));
            }
            *(f32x4*)(Cp + (size_t)row * Dd + col) = v;
        }
    }
}

// ---------- fused B+C GEMM: PERSISTENT 256x256, BK=64, 64-tile loop ----------
// r3/r5 invariance (166us regardless of staging depth/vmcnt slack) + r4
// (occupancy 2x -> slower) exonerate load-latency and co-residency. Our 827 TF
// matches the guide's measured K=1024 ceiling for this structure (m248: 848);
// m201's 1563 needed a 64-tile K-loop. Fix: persistent blocks. Grid = NY*32
// (=256, 1/CU). Each block owns 1 row-panel x 4 ADJACENT col-panels and runs
// ONE continuous 64-tile pipeline; at panel ends the acc is flushed inline
// while staging continues (wrapped addressing, W ptr advances +256*K). vmcnt
// stays in-order-correct: per-panel vmcnt(8) after an epilogue drains the
// ~36 store/bias ops + older loads, keeping the newest 8 staged loads alive.
// XCD decode: per XCD, 32 blocks = 4 col-groups x NY rows -> 4 active W
// panels (2 MB) in L2; each panel L2-hit by NY blocks.
__global__ __launch_bounds__(512, 2) void gemm256_bc(
    const bf16_t* __restrict__ Abase, int CL, int l0, int K,
    const bf16_t* __restrict__ WB, const bf16_t* __restrict__ WC,
    const float* __restrict__ bB, const float* __restrict__ bC,
    bf16_t* __restrict__ OB, bf16_t* __restrict__ OC)
{
    extern __shared__ char smem[];   // A: [0,96K) 3x32K; B: [96K,160K) 2x32K
    char* const smA = smem;
    char* const smB = smem + 98304;
    const int tid = threadIdx.x;

    // persistent decode: id -> (xcd, w) -> col-group xg (4 panels) + row yb
    const int NY = (2 * CL) >> 8;          // row-panels
    const int id = blockIdx.x;             // grid = NY*32
    const int xcd = id & 7;
    const int w = id >> 3;                 // 0 .. NY*4-1
    const int xg = xcd * 4 + w / NY;       // col-group 0..31 (4 panels each)
    const int yb = w % NY;

    const int rglob = yb * 256;
    const int batch = rglob / CL;
    const int rin = rglob % CL;
    const bf16_t* Ap = Abase + ((size_t)batch * Ll + l0 + rin) * K;

    // col-group entirely within B (xg<16) or C (xg>=16)
    const int x0 = xg * 4;                 // first col-panel (of 128)
    const bf16_t* Wp0; const float* bias0; bf16_t* Co; int bnBase;
    if (x0 < 64) { Wp0 = WB; bias0 = bB; Co = OB; bnBase = x0 * 256; }
    else         { Wp0 = WC; bias0 = bC; Co = OC; bnBase = (x0 - 64) * 256; }
    const bf16_t* WpB = Wp0 + (size_t)bnBase * K;    // panel j at + j*256*K
    bf16_t* Cp = Co + (size_t)rglob * NB;

    const int lane = tid & 63;
    const int wid = tid >> 6;
    const int wr = wid >> 2;       // 0..1  (M half)
    const int wc = wid & 3;        // 0..3  (N quarter)
    const int lr = lane & 15;
    const int lq = lane >> 4;
    const int NTK = K >> 6;        // K-tiles per panel (16)

    // staging: 2 chunks of 16B per thread per half-tile (128 rows x 64 k)
    const int c0 = tid, c1 = tid + 512;
    const int r0 = c0 >> 3, r1 = c1 >> 3;
    const int kb0 = ((c0 & 7) << 3) ^ ((r0 & 7) << 3);   // inverse-swizzled src
    const int kb1 = ((c1 & 7) << 3) ^ ((r1 & 7) << 3);

    // stage half-tile h of (panel jn, k-tile tn) into slot
    auto stageA = [&](int tn, int slot, int h) {
        gld_lds16(Ap + (size_t)(h * 128 + r0) * K + tn * 64 + kb0,
                  smA + slot * 32768 + h * 16384 + c0 * 16);
        gld_lds16(Ap + (size_t)(h * 128 + r1) * K + tn * 64 + kb1,
                  smA + slot * 32768 + h * 16384 + c1 * 16);
    };
    auto stageB = [&](int jn, int tn, int slot, int h) {
        const bf16_t* Wj = WpB + (size_t)jn * 256 * K;
        gld_lds16(Wj + (size_t)(h * 128 + r0) * K + tn * 64 + kb0,
                  smB + slot * 32768 + h * 16384 + c0 * 16);
        gld_lds16(Wj + (size_t)(h * 128 + r1) * K + tn * 64 + kb1,
                  smB + slot * 32768 + h * 16384 + c1 * 16);
    };

    // prologue: (j0,t0) and (j0,t1); vmcnt(8) drains tile 0's operands
    stageA(0, 0, 0); stageA(0, 0, 1);
    stageB(0, 0, 0, 0); stageB(0, 0, 0, 1);
    stageA(1, 1, 0); stageA(1, 1, 1);
    stageB(0, 1, 1, 0); stageB(0, 1, 1, 1);
    asm volatile("s_waitcnt vmcnt(8)" ::: "memory");
    __builtin_amdgcn_s_barrier();

    f32x4 acc[8][4] = {};
    const int xsw = (lr & 7) << 4;     // read-side XOR swizzle (bytes)
    int as_rd = 0, as_wr = 2;

    for (int j = 0; j < 4; ++j) {
        for (int tt = 0; tt < NTK; ++tt) {
            const int v = j * NTK + tt;          // virtual tile 0..4*NTK-1
            const bool more2 = (v + 2 < 4 * NTK);
            const bool more1 = (v + 1 < 4 * NTK);
            int tn = tt + 2, jn = j;
            if (tn >= NTK) { tn -= NTK; ++jn; }  // staging coords for v+2

            const char* Ard = smA + as_rd * 32768;
            const char* Brd = smB + (tt & 1) * 32768;   // v&1 == tt&1 (NTK even)

            bf16x8 bfr[2][4];
#pragma unroll
            for (int p = 0; p < 4; ++p) {
                if (p == 0) { if (more2) stageA(tn, as_wr, 0); }
                if (p == 1) { if (more2) stageA(tn, as_wr, 1); }
                if (p == 2) { if (more2) stageB(jn, tn, (tt & 1), 0); }
                if (p == 3) { if (more2) stageB(jn, tn, (tt & 1), 1); }

                if (p == 0) {
#pragma unroll
                    for (int ks = 0; ks < 2; ++ks)
#pragma unroll
                        for (int ni = 0; ni < 4; ++ni)
                            bfr[ks][ni] = *(const bf16x8*)(Brd +
                                (wc * 64 + ni * 16 + lr) * 128 +
                                ((ks * 64 + lq * 16) ^ xsw));
                }
                bf16x8 a0k0 = *(const bf16x8*)(Ard +
                    (wr * 128 + (2 * p) * 16 + lr) * 128 + ((lq * 16) ^ xsw));
                bf16x8 a0k1 = *(const bf16x8*)(Ard +
                    (wr * 128 + (2 * p) * 16 + lr) * 128 + ((64 + lq * 16) ^ xsw));
                bf16x8 a1k0 = *(const bf16x8*)(Ard +
                    (wr * 128 + (2 * p + 1) * 16 + lr) * 128 + ((lq * 16) ^ xsw));
                bf16x8 a1k1 = *(const bf16x8*)(Ard +
                    (wr * 128 + (2 * p + 1) * 16 + lr) * 128 + ((64 + lq * 16) ^ xsw));

                __builtin_amdgcn_s_barrier();
                __builtin_amdgcn_s_setprio(1);
#pragma unroll
                for (int ni = 0; ni < 4; ++ni) {   // SWAPPED operands
                    acc[2 * p][ni] = __builtin_amdgcn_mfma_f32_16x16x32_bf16(
                        bfr[0][ni], a0k0, acc[2 * p][ni], 0, 0, 0);
                    acc[2 * p][ni] = __builtin_amdgcn_mfma_f32_16x16x32_bf16(
                        bfr[1][ni], a0k1, acc[2 * p][ni], 0, 0, 0);
                    acc[2 * p + 1][ni] = __builtin_amdgcn_mfma_f32_16x16x32_bf16(
                        bfr[0][ni], a1k0, acc[2 * p + 1][ni], 0, 0, 0);
                    acc[2 * p + 1][ni] = __builtin_amdgcn_mfma_f32_16x16x32_bf16(
                        bfr[1][ni], a1k1, acc[2 * p + 1][ni], 0, 0, 0);
                }
                __builtin_amdgcn_s_setprio(0);
                if (p == 3) {
                    if (more2)
                        asm volatile("s_waitcnt vmcnt(8)" ::: "memory");
                    else if (more1)
                        asm volatile("s_waitcnt vmcnt(0)" ::: "memory");
                }
                __builtin_amdgcn_s_barrier();
            }
            ++as_rd; if (as_rd == 3) as_rd = 0;
            ++as_wr; if (as_wr == 3) as_wr = 0;
        }

        // inline panel epilogue (registers + global only; no LDS, no barrier).
        // swapped D: row = wr*128+mi*16+lr, cols = bnj+wc*64+ni*16+lq*4 .. +3
        {
            const int bnj = bnBase + j * 256;
            float4 bv[4];
#pragma unroll
            for (int ni = 0; ni < 4; ++ni)
                bv[ni] = *(const float4*)&bias0[bnj + wc * 64 + ni * 16 + lq * 4];
#pragma unroll
            for (int mi = 0; mi < 8; ++mi) {
                const size_t rowoff = (size_t)(wr * 128 + mi * 16 + lr) * NB;
#pragma unroll
                for (int ni = 0; ni < 4; ++ni) {
                    const int col = bnj + wc * 64 + ni * 16 + lq * 4;
                    bf16x4 o = {(bf16_t)(acc[mi][ni][0] + bv[ni].x),
                                (bf16_t)(acc[mi][ni][1] + bv[ni].y),
                                (bf16_t)(acc[mi][ni][2] + bv[ni].z),
                                (bf16_t)(acc[mi][ni][3] + bv[ni].w)};
                    *(bf16x4*)(Cp + rowoff + col) = o;
                }
            }
#pragma unroll
            for (int mi = 0; mi < 8; ++mi)
#pragma unroll
                for (int ni = 0; ni < 4; ++ni)
                    acc[mi][ni] = f32x4{0.f, 0.f, 0.f, 0.f};
        }
    }
}

// ---------- scan pass A: per-segment local scan (h0 = 0) ----------
__global__ __launch_bounds__(256) void scan_seg_local(
    const float* __restrict__ u, const float* __restrict__ dt,
    const bf16_t* __restrict__ Bt_c, const float* __restrict__ log_A,
    float* __restrict__ pseg, float* __restrict__ hseg, int CL, int l0)
{
    const int tid = threadIdx.x;
    const int g = tid >> 4, n = tid & 15;
    const int gid = blockIdx.x * 16 + g;
    const int ch = gid & (NCH - 1);
    const int s = gid >> 11;
    const int b = ch >> 10, d = ch & (Dd - 1);

    const float A = -__expf(log_A[d * Nn + n]);
    const float rA = 1.f / A;

    size_t idx_bn = (size_t)(b * CL + s * SL) * NB + d * Nn + n;
    size_t idx_u = ((size_t)b * Ll + l0 + s * SL) * Dd + d;

    float p = 1.f, h = 0.f;
    for (int l = 0; l < SL; ++l) {
        const float dtv = dt[idx_u];
        const float uv = u[idx_u];
        const float bv = (float)Bt_c[idx_bn];
        const float a = __expf(dtv * A);
        p *= a;
        h = a * h + (a - 1.f) * rA * bv * uv;
        idx_bn += NB; idx_u += Dd;
    }
    const size_t o = ((size_t)s * NCH + ch) * Nn + n;
    pseg[o] = p;
    hseg[o] = h;
}

// ---------- scan pass B: sequential combine across segments ----------
__global__ __launch_bounds__(256) void scan_combine(
    const float* __restrict__ pseg, const float* __restrict__ hseg,
    float* __restrict__ hin_arr, float* __restrict__ h_state,
    int NSEG, int l0)
{
    const int t = blockIdx.x * 256 + threadIdx.x;
    float hin = (l0 == 0) ? 0.f : h_state[t];
    for (int s = 0; s < NSEG; ++s) {
        const size_t o = (size_t)s * (NCH * Nn) + t;
        hin_arr[o] = hin;
        hin = pseg[o] * hin + hseg[o];
    }
    h_state[t] = hin;
}

// ---------- scan pass C: re-run segment from correct h_in, emit y ----------
__global__ __launch_bounds__(256) void scan_seg_final(
    const float* __restrict__ u, const float* __restrict__ dt,
    const bf16_t* __restrict__ Bt_c, const bf16_t* __restrict__ Ct_c,
    const float* __restrict__ log_A, const float* __restrict__ D_skip,
    const float* __restrict__ hin_arr, float* __restrict__ y, int CL, int l0)
{
    const int tid = threadIdx.x;
    const int g = tid >> 4, n = tid & 15;
    const int gid = blockIdx.x * 16 + g;
    const int ch = gid & (NCH - 1);
    const int s = gid >> 11;
    const int b = ch >> 10, d = ch & (Dd - 1);

    const float A = -__expf(log_A[d * Nn + n]);
    const float rA = 1.f / A;
    const float Dsk = D_skip[d];

    size_t idx_bn = (size_t)(b * CL + s * SL) * NB + d * Nn + n;
    size_t idx_u = ((size_t)b * Ll + l0 + s * SL) * Dd + d;

    float h = hin_arr[((size_t)s * NCH + ch) * Nn + n];
    for (int l = 0; l < SL; ++l) {
        const float dtv = dt[idx_u];
        const float uv = u[idx_u];
        const float bv = (float)Bt_c[idx_bn];
        const float cv = (float)Ct_c[idx_bn];
        const float a = __expf(dtv * A);
        h = a * h + (a - 1.f) * rA * bv * uv;
        float p = cv * h;
        p += __shfl_xor(p, 1);
        p += __shfl_xor(p, 2);
        p += __shfl_xor(p, 4);
        p += __shfl_xor(p, 8);
        if (n == 0) y[idx_u] = p + Dsk * uv;
        idx_bn += NB; idx_u += Dd;
    }
}

// ---------- host ----------
static inline size_t al256(size_t x) { return (x + 255) & ~(size_t)255; }

extern "C" void kernel_launch(void* const* d_in, const int* in_sizes, int n_in,
                              void* d_out, int out_size, void* d_ws, size_t ws_size,
                              hipStream_t stream) {
    const float* u       = (const float*)d_in[0];
    const float* log_A   = (const float*)d_in[1];
    const float* D_skip  = (const float*)d_in[2];
    const float* dt_bias = (const float*)d_in[3];
    const float* W_dt    = (const float*)d_in[4];
    const float* b_dt    = (const float*)d_in[5];
    const float* W_B     = (const float*)d_in[6];
    const float* b_B     = (const float*)d_in[7];
    const float* W_C     = (const float*)d_in[8];
    const float* b_C     = (const float*)d_in[9];
    float* y = (float*)d_out;

    // dynamic LDS opt-in (capture-safe host calls)
    hipFuncSetAttribute(reinterpret_cast<const void*>(gemm256_bc),
                        hipFuncAttributeMaxDynamicSharedMemorySize, 163840);
    hipFuncSetAttribute(reinterpret_cast<const void*>(gemm_dt),
                        hipFuncAttributeMaxDynamicSharedMemorySize, 81920);

    const size_t sz_ubf  = al256((size_t)Bb * Ll * Dd * 2);
    const size_t sz_w    = al256((size_t)NB * Dd * 2);
    const size_t sz_h    = al256((size_t)NCH * Nn * 4);
    const size_t sz_dtf  = al256((size_t)Bb * Ll * Dd * 4);
    const size_t sz_ucat = al256((size_t)Bb * Ll * KCAT * 2);
    const size_t sz_wcat = al256((size_t)Dd * KCAT * 2);

    int CL = 128;
    const int cands[5] = {2048, 1024, 512, 256, 128};
    for (int i = 0; i < 5; ++i) {
        const int c = cands[i];
        const int nseg = c / SL;
        const size_t seg = 3 * al256((size_t)nseg * NCH * Nn * 4);
        const size_t chunk = 2 * al256((size_t)2 * c * NB * 2);
        const size_t ovl = sz_ucat + sz_wcat;
        const size_t need = sz_ubf + 2 * sz_w + sz_h + sz_dtf + seg +
                            (chunk > ovl ? chunk : ovl);
        if (need <= ws_size) { CL = c; break; }
    }
    const int NSEG = CL / SL;

    char* p = (char*)d_ws;
    bf16_t* u_bf   = (bf16_t*)p; p += sz_ubf;
    bf16_t* wB_bf  = (bf16_t*)p; p += sz_w;
    bf16_t* wC_bf  = (bf16_t*)p; p += sz_w;
    float* h_state = (float*)p; p += sz_h;
    float* dt_full = (float*)p; p += sz_dtf;
    const size_t sz_seg1 = al256((size_t)NSEG * NCH * Nn * 4);
    float* pseg    = (float*)p; p += sz_seg1;
    float* hseg    = (float*)p; p += sz_seg1;
    float* hin_arr = (float*)p; p += sz_seg1;
    char* chunk0 = p;
    bf16_t* Bt_c = (bf16_t*)chunk0;
    bf16_t* Ct_c = (bf16_t*)(chunk0 + al256((size_t)2 * CL * NB * 2));
    bf16_t* u_cat = (bf16_t*)chunk0;
    bf16_t* w_cat = (bf16_t*)(chunk0 + sz_ucat);

    cvt_bf16<<<2048, 256, 0, stream>>>(W_B, wB_bf, NB * Dd / 4);
    cvt_bf16<<<2048, 256, 0, stream>>>(W_C, wC_bf, NB * Dd / 4);
    build_ucat<<<Bb * Ll * Dd / 4 / 256, 256, 0, stream>>>(u, u_cat, u_bf);
    build_wcat<<<Dd * Dd / 4 / 256, 256, 0, stream>>>(W_dt, w_cat);

    // dt GEMM: 128x128 tiles, deep-pipelined, 2 blocks/CU
    gemm_dt<<<dim3(Dd / 128, Bb * Ll / 128), 512, 81920, stream>>>(
        u_cat, KCAT, w_cat, b_dt, dt_bias, dt_full);

    const bool use256 = (CL % 256 == 0);
    for (int l0 = 0; l0 < Ll; l0 += CL) {
        if (use256) {
            const int NY = 2 * CL / 256;
            gemm256_bc<<<dim3(NY * 32), 512, 163840, stream>>>(
                u_bf, CL, l0, Dd, wB_bf, wC_bf, b_B, b_C, Bt_c, Ct_c);
        } else {
            gemm_mfma<0, bf16_t><<<dim3(NB / 128, 2 * CL / 128), 256, 0, stream>>>(
                u_bf, CL, l0, Dd, wB_bf, b_B, nullptr, Bt_c, NB);
            gemm_mfma<0, bf16_t><<<dim3(NB / 128, 2 * CL / 128), 256, 0, stream>>>(
                u_bf, CL, l0, Dd, wC_bf, b_C, nullptr, Ct_c, NB);
        }
        scan_seg_local<<<dim3(128 * NSEG), 256, 0, stream>>>(
            u, dt_full, Bt_c, log_A, pseg, hseg, CL, l0);
        scan_combine<<<dim3(128), 256, 0, stream>>>(
            pseg, hseg, hin_arr, h_state, NSEG, l0);
        scan_seg_final<<<dim3(128 * NSEG), 256, 0, stream>>>(
            u, dt_full, Bt_c, Ct_c, log_A, D_skip, hin_arr, y, CL, l0);
    }
}